// Round 7
// baseline (197.061 us; speedup 1.0000x reference)
//
#include <hip/hip_runtime.h>
#include <math.h>

#define ROW_LEN 8192
#define TOPK 8
#define THREADS 256
#define NWAVES 4
#define WCAP 64        // per-wave cap; E[count/wave]≈13 at T0=2.5 on N(0,1)
#define T0 2.5f        // static threshold; E[#>T0 per row]≈51; exact guard below

__global__ __launch_bounds__(THREADS) void topk_rows_kernel(
        const float* __restrict__ x,
        float* __restrict__ out_vals,     // [n_rows, 8] float
        float* __restrict__ out_idx,      // [n_rows, 8] indices stored as float
        int n_rows) {
    const int row  = blockIdx.x;
    const int tid  = threadIdx.x;
    const int lane = tid & 63;
    const int wave = tid >> 6;
    if (row >= n_rows) return;

    const float4* rowp = (const float4*)(x + (size_t)row * ROW_LEN);

    __shared__ float cv[NWAVES][WCAP];
    __shared__ int   ci[NWAVES][WCAP];
    __shared__ int   wn[NWAVES];
    if (lane == 0) wn[wave] = 0;   // own wave's counter; intra-wave DS program order

    // ---- single streaming pass: load + inline candidate collection.
    // Pass branch is per-lane rare (p≈0.006/elem) -> exec-masked, cheap.
    // No per-thread max, no shuffles, no second pass over the data. ----
#pragma unroll
    for (int k = 0; k < 8; k++) {
        float4 f = rowp[k * THREADS + tid];
        float vv[4] = {f.x, f.y, f.z, f.w};
#pragma unroll
        for (int j = 0; j < 4; j++) {
            if (vv[j] > T0) {
                int p = atomicAdd(&wn[wave], 1);
                if (p < WCAP) {              // memory-safety clamp
                    cv[wave][p] = vv[j];
                    ci[wave][p] = 4 * (k * THREADS + tid) + j;
                }
            }
        }
    }
    __syncthreads();   // the only barrier

    if (wave != 0) return;   // waves 1-3 retire immediately

    // ---- exactness guard:
    // n >= 8  =>  there are >=8 elements > T0  =>  8th-largest v8 > T0
    //         =>  every element >= v8 (incl. ties) is a candidate  => exact.
    int cnt[NWAVES];
    bool ovf = false;
    int n = 0;
#pragma unroll
    for (int w = 0; w < NWAVES; w++) {
        int c = wn[w];
        ovf |= (c > WCAP);
        cnt[w] = (c > WCAP) ? WCAP : c;
        n += cnt[w];
    }

    if (n >= TOPK && !ovf) {
        // ---- rank-select: rank by (value desc, index asc) — exact
        // lax.top_k tie order; ranks unique via index tiebreak ->
        // exactly 8 race-free writers. n≈51 -> ~0.3 µs. ----
        for (int c = lane; c < n; c += 64) {
            int w = 0, off = c;
            while (off >= cnt[w]) { off -= cnt[w]; w++; }
            const float myv = cv[w][off];
            const int   myi = ci[w][off];
            int rank = 0;
#pragma unroll
            for (int w2 = 0; w2 < NWAVES; w2++) {
                const int nn = cnt[w2];
                for (int j = 0; j < nn; j++) {
                    const float ov = cv[w2][j];
                    const int   oi = ci[w2][j];
                    rank += (ov > myv) || (ov == myv && oi < myi);
                }
            }
            if (rank < TOPK) {
                out_vals[(size_t)row * TOPK + rank] = myv;
                out_idx[(size_t)row * TOPK + rank]  = (float)myi;
            }
        }
    } else if (lane == 0) {
        // ---- exact serial fallback (probability ~1e-9/row; never fast-
        // path-wrong). Insertion top-8 with (value desc, index asc):
        // scanning i ascending + strict '>' replacement preserves the
        // stable tie order. ----
        float bv[TOPK]; int bi[TOPK];
#pragma unroll
        for (int i = 0; i < TOPK; i++) { bv[i] = -INFINITY; bi[i] = 0; }
        const float* rp = x + (size_t)row * ROW_LEN;
        for (int i = 0; i < ROW_LEN; i++) {
            float vv = rp[i];
            if (vv > bv[TOPK - 1]) {
                int j = TOPK - 1;
                while (j > 0 && bv[j - 1] < vv) {
                    bv[j] = bv[j - 1]; bi[j] = bi[j - 1]; j--;
                }
                bv[j] = vv; bi[j] = i;
            }
        }
#pragma unroll
        for (int j = 0; j < TOPK; j++) {
            out_vals[(size_t)row * TOPK + j] = bv[j];
            out_idx[(size_t)row * TOPK + j] = (float)bi[j];
        }
    }
}

extern "C" void kernel_launch(void* const* d_in, const int* in_sizes, int n_in,
                              void* d_out, int out_size, void* d_ws, size_t ws_size,
                              hipStream_t stream) {
    const float* x = (const float*)d_in[0];
    float* out = (float*)d_out;
    const int n_rows = in_sizes[0] / ROW_LEN;          // 4096
    float* out_vals = out;                              // values, flat [n_rows*8]
    float* out_idx  = out + (size_t)n_rows * TOPK;      // indices (as float)

    topk_rows_kernel<<<n_rows, THREADS, 0, stream>>>(x, out_vals, out_idx, n_rows);
}